// Round 1
// baseline (233.709 us; speedup 1.0000x reference)
//
#include <hip/hip_runtime.h>
#include <math.h>

#define T_TOKENS 16384
#define D_DIM    2048
#define E_EXP    64
#define TOPK     8
#define NS       4                   // split-K slices
#define KC       32                  // k per chunk
#define NCH      (D_DIM / NS / KC)   // 16 chunks per slice
#define TT       64                  // tokens per block

typedef __attribute__((ext_vector_type(8))) short bf16x8;
typedef __attribute__((ext_vector_type(4))) float f32x4;

__device__ __forceinline__ unsigned short bf16rne(float f) {
  unsigned u = __builtin_bit_cast(unsigned, f);
  unsigned r = u + 0x7fffu + ((u >> 16) & 1u);
  return (unsigned short)(r >> 16);
}
__device__ __forceinline__ float bf16f(unsigned short h) {
  return __builtin_bit_cast(float, (unsigned)h << 16);
}

// ---------------- Kernel 0: pre-convert gate_w to frag-ordered bf16 hi/lo ----
// entry id = ((c*4 + kq)*64 + e): c = k/32 chunk, kq = k-quad, e = expert.
// Entry = 8 bf16 (16 B) = g[e][c*32 + kq*8 .. +7]. Also zeroes counts region.
__global__ __launch_bounds__(256) void convert_g_kernel(
    const float* __restrict__ gw, unsigned short* __restrict__ ph,
    unsigned short* __restrict__ pl, float* __restrict__ counts_zero)
{
  const int id = blockIdx.x * 256 + threadIdx.x;   // 0..16383
  if (blockIdx.x == 0 && threadIdx.x < E_EXP) counts_zero[threadIdx.x] = 0.0f;

  const int e  = id & 63;
  const int kq = (id >> 6) & 3;
  const int c  = id >> 8;
  const float* gp = &gw[(size_t)e * D_DIM + c * 32 + kq * 8];
  float4 v0 = *(const float4*)&gp[0];
  float4 v1 = *(const float4*)&gp[4];
  const float xs[8] = {v0.x, v0.y, v0.z, v0.w, v1.x, v1.y, v1.z, v1.w};
  bf16x8 hi, lo;
  #pragma unroll
  for (int j = 0; j < 8; ++j) {
    unsigned short h = bf16rne(xs[j]);
    hi[j] = (short)h;
    lo[j] = (short)bf16rne(xs[j] - bf16f(h));
  }
  *(bf16x8*)&ph[(size_t)id * 8] = hi;
  *(bf16x8*)&pl[(size_t)id * 8] = lo;
}

// ---------------- Kernel 1: partial logits via split-bf16 MFMA ----------------
// grid (T/64, NS), 256 thr = 4 waves. Block tile 64 tok x 64 exp; wave w owns
// tokens [w*16, w*16+16). LDS-FREE version: waves share NOTHING (each owns
// disjoint token rows), so the old LDS staging was pure transpose overhead
// (2 barriers + LDS round-trip per chunk). A-frag layout (row=l15, k=quad*8+j)
// is loaded DIRECTLY from global: lane reads 32 contiguous bytes; the 4 quads
// of a wave cover each token row as one fully-used 128 B line — same DRAM
// granularity as the staged path, zero barriers, fully independent waves.
//   - depth-1 register prefetch of chunk c+1's A while chunk c computes
//   - all 8 B-frags (L2-hot packed bf16) loaded up-front each chunk; the
//     ~130-VALU hi/lo split of A hides their L2 latency
//   - 12 MFMA: (ah*bh + al*bh + ah*bl) x 4 expert tiles  (numerics unchanged)
__global__ __launch_bounds__(256, 4) void moe_logits_kernel(
    const float* __restrict__ x, const unsigned short* __restrict__ ph,
    const unsigned short* __restrict__ pl, float* __restrict__ part)
{
  const int tid  = threadIdx.x;
  const int wave = tid >> 6;
  const int lane = tid & 63;
  const int l15  = lane & 15;
  const int quad = lane >> 4;
  const int ks   = blockIdx.y;
  const int k0   = ks * (D_DIM / NS);
  const int tokw = blockIdx.x * TT + wave * 16;

  // A source: this lane's token row, this quad's 32-byte k-segment
  const float* xg = &x[(size_t)(tokw + l15) * D_DIM + k0 + quad * 8];

  // B source: frag-packed bf16 hi/lo (identical math to previous kernel)
  const unsigned short* bh_p = &ph[(((size_t)(k0 >> 5) * 4 + quad) * 64 + l15) * 8];
  const unsigned short* bl_p = &pl[(((size_t)(k0 >> 5) * 4 + quad) * 64 + l15) * 8];

  f32x4 acc[4];
  #pragma unroll
  for (int et = 0; et < 4; ++et) acc[et] = (f32x4){0.f, 0.f, 0.f, 0.f};

  // ---- prologue: load chunk 0's A ----
  float4 p0 = *(const float4*)xg;
  float4 p1 = *(const float4*)(xg + 4);

  #pragma unroll 1
  for (int c = 0; c < NCH; ++c) {
    // ---- all 8 B-frags for this chunk (L2-hot, 256 B segments) ----
    const unsigned short* ch = bh_p + (size_t)c * 2048;
    const unsigned short* cl = bl_p + (size_t)c * 2048;
    bf16x8 bh[4], bl[4];
    #pragma unroll
    for (int et = 0; et < 4; ++et) {
      bh[et] = *(const bf16x8*)&ch[et * 128];
      bl[et] = *(const bf16x8*)&cl[et * 128];
    }

    // ---- prefetch next chunk's A (in flight during convert + MFMA) ----
    float4 n0 = {0.f, 0.f, 0.f, 0.f}, n1 = {0.f, 0.f, 0.f, 0.f};
    if (c + 1 < NCH) {
      n0 = *(const float4*)(xg + (c + 1) * KC);
      n1 = *(const float4*)(xg + (c + 1) * KC + 4);
    }

    // ---- split current A chunk to hi/lo bf16 (register-only) ----
    const float xs[8] = {p0.x, p0.y, p0.z, p0.w, p1.x, p1.y, p1.z, p1.w};
    bf16x8 ah, al;
    #pragma unroll
    for (int j = 0; j < 8; ++j) {
      unsigned short h = bf16rne(xs[j]);
      ah[j] = (short)h;
      al[j] = (short)bf16rne(xs[j] - bf16f(h));
    }

    // ---- 12 MFMAs ----
    #pragma unroll
    for (int et = 0; et < 4; ++et) {
      acc[et] = __builtin_amdgcn_mfma_f32_16x16x32_bf16(ah, bh[et], acc[et], 0, 0, 0);
      acc[et] = __builtin_amdgcn_mfma_f32_16x16x32_bf16(al, bh[et], acc[et], 0, 0, 0);
      acc[et] = __builtin_amdgcn_mfma_f32_16x16x32_bf16(ah, bl[et], acc[et], 0, 0, 0);
    }

    p0 = n0; p1 = n1;   // dead on last iteration
  }

  // ---- store partials: D row(m) = quad*4 + r (token), col(n) = l15 (expert) ----
  #pragma unroll
  for (int et = 0; et < 4; ++et) {
    #pragma unroll
    for (int r = 0; r < 4; ++r) {
      const size_t t = (size_t)tokw + quad * 4 + r;
      part[((size_t)ks * T_TOKENS + t) * E_EXP + et * 16 + l15] = acc[et][r];
    }
  }
}

// ---------------- Kernel 2: reduce + bias, top-8, softmax, counts ----------------
__global__ __launch_bounds__(64) void topk_kernel(
    const float* __restrict__ part, const float* __restrict__ bias,
    float* __restrict__ out)
{
  __shared__ unsigned hist[E_EXP];
  const int tid = threadIdx.x;            // 0..63
  const int t = blockIdx.x * 64 + tid;
  hist[tid] = 0;
  __syncthreads();

  float l[E_EXP];
  #pragma unroll
  for (int j = 0; j < E_EXP / 4; ++j) {
    float4 b = *(const float4*)&bias[j * 4];
    l[4*j] = b.x; l[4*j+1] = b.y; l[4*j+2] = b.z; l[4*j+3] = b.w;
  }
  #pragma unroll 2
  for (int ks = 0; ks < NS; ++ks) {
    const float4* p = (const float4*)&part[((size_t)ks * T_TOKENS + t) * E_EXP];
    #pragma unroll
    for (int j = 0; j < E_EXP / 4; ++j) {
      float4 v = p[j];
      l[4*j] += v.x; l[4*j+1] += v.y; l[4*j+2] += v.z; l[4*j+3] += v.w;
    }
  }

  float tv[TOPK]; int tix[TOPK];
  unsigned long long used = 0ull;
  #pragma unroll
  for (int k = 0; k < TOPK; ++k) {
    float best = -INFINITY; int bi = 0;
    #pragma unroll
    for (int j = 0; j < E_EXP; ++j) {
      bool ok = (((used >> j) & 1ull) == 0ull) && (l[j] > best);  // strict >: lowest index wins ties
      best = ok ? l[j] : best;
      bi   = ok ? j : bi;
    }
    tv[k] = best; tix[k] = bi;
    used |= (1ull << bi);
  }

  float m = tv[0], s = 0.0f, w[TOPK];
  #pragma unroll
  for (int k = 0; k < TOPK; ++k) { w[k] = expf(tv[k] - m); s += w[k]; }
  float inv = 1.0f / s;

  #pragma unroll
  for (int k = 0; k < TOPK; ++k) {
    out[(size_t)t * TOPK + k] = (float)tix[k];                        // indices as fp32
    out[(size_t)T_TOKENS * TOPK + (size_t)t * TOPK + k] = w[k] * inv; // weights
  }

  #pragma unroll
  for (int k = 0; k < TOPK; ++k) atomicAdd(&hist[tix[k]], 1u);
  __syncthreads();
  atomicAdd(&out[2 * (size_t)T_TOKENS * TOPK + tid], (float)hist[tid]);
}

extern "C" void kernel_launch(void* const* d_in, const int* in_sizes, int n_in,
                              void* d_out, int out_size, void* d_ws, size_t ws_size,
                              hipStream_t stream) {
  const float* x    = (const float*)d_in[0];
  const float* gw   = (const float*)d_in[1];
  const float* bias = (const float*)d_in[2];
  float* out  = (float*)d_out;

  // ws layout: part (NS*4 MB) | ph (256 KB) | pl (256 KB)
  float* part = (float*)d_ws;
  const size_t part_elems = (size_t)NS * T_TOKENS * E_EXP;
  unsigned short* ph = (unsigned short*)((char*)d_ws + part_elems * sizeof(float));
  unsigned short* pl = ph + (size_t)E_EXP * D_DIM;

  convert_g_kernel<<<dim3(E_EXP * D_DIM / 8 / 256), dim3(256), 0, stream>>>(
      gw, ph, pl, out + 2 * (size_t)T_TOKENS * TOPK);
  moe_logits_kernel<<<dim3(T_TOKENS / TT, NS), dim3(256), 0, stream>>>(
      x, ph, pl, part);
  topk_kernel<<<dim3(T_TOKENS / 64), dim3(64), 0, stream>>>(part, bias, out);
}

// Round 2
// 215.345 us; speedup vs baseline: 1.0853x; 1.0853x over previous
//
#include <hip/hip_runtime.h>
#include <math.h>

#define T_TOKENS 16384
#define D_DIM    2048
#define E_EXP    64
#define TOPK     8
#define NS       4                   // K slices (now across waves within a block)
#define KC       32                  // k per chunk
#define NCH      (D_DIM / NS / KC)   // 16 chunks per slice
#define TT       64                  // tokens per block
#define TOKP     68                  // token stride in LDS slab (17 float4s: 16B-aligned rows)

typedef __attribute__((ext_vector_type(8))) short bf16x8;
typedef __attribute__((ext_vector_type(4))) float f32x4;

__device__ __forceinline__ unsigned short bf16rne(float f) {
  unsigned u = __builtin_bit_cast(unsigned, f);
  unsigned r = u + 0x7fffu + ((u >> 16) & 1u);
  return (unsigned short)(r >> 16);
}
__device__ __forceinline__ float bf16f(unsigned short h) {
  return __builtin_bit_cast(float, (unsigned)h << 16);
}

// ---------------- Kernel 0: pre-convert gate_w to frag-ordered bf16 hi/lo ----
// entry id = ((c*4 + kq)*64 + e): c = k/32 chunk, kq = k-quad, e = expert.
// Entry = 8 bf16 (16 B) = g[e][c*32 + kq*8 .. +7]. Also zeroes counts region.
__global__ __launch_bounds__(256) void convert_g_kernel(
    const float* __restrict__ gw, unsigned short* __restrict__ ph,
    unsigned short* __restrict__ pl, float* __restrict__ counts_zero)
{
  const int id = blockIdx.x * 256 + threadIdx.x;   // 0..16383
  if (blockIdx.x == 0 && threadIdx.x < E_EXP) counts_zero[threadIdx.x] = 0.0f;

  const int e  = id & 63;
  const int kq = (id >> 6) & 3;
  const int c  = id >> 8;
  const float* gp = &gw[(size_t)e * D_DIM + c * 32 + kq * 8];
  float4 v0 = *(const float4*)&gp[0];
  float4 v1 = *(const float4*)&gp[4];
  const float xs[8] = {v0.x, v0.y, v0.z, v0.w, v1.x, v1.y, v1.z, v1.w};
  bf16x8 hi, lo;
  #pragma unroll
  for (int j = 0; j < 8; ++j) {
    unsigned short h = bf16rne(xs[j]);
    hi[j] = (short)h;
    lo[j] = (short)bf16rne(xs[j] - bf16f(h));
  }
  *(bf16x8*)&ph[(size_t)id * 8] = hi;
  *(bf16x8*)&pl[(size_t)id * 8] = lo;
}

// ---------------- Kernel 1 (fused): logits + reduce + top-8 + counts ----------
// grid = T/64 = 256 blocks (1/CU), 1024 thr = 16 waves = 4 token-groups x 4
// K-slices. Wave (wg, wsl): tokens [blk*64 + wg*16, +16), k in [wsl*512, +512).
// K-loop is the validated LDS-free body (no barriers; waves fully independent;
// depth-1 A prefetch; B frag-packed bf16 hi/lo from L2; 12 MFMA/chunk, numerics
// identical to the 3-kernel version). Epilogue replaces the part-buffer round
// trip (33 MB HBM) and the separate 1-wave/CU topk kernel:
//   acc -> LDS slab[slice][expert][token] (stride 68, b128-aligned)
//   barrier; 1024-thr reduce (order: bias, +s0, +s1, +s2, +s3 — unchanged)
//   barrier; wave 0: per-token bitmask top-8 + softmax + hist + global atomics.
__global__ __launch_bounds__(1024, 4) void moe_fused_kernel(
    const float* __restrict__ x, const unsigned short* __restrict__ ph,
    const unsigned short* __restrict__ pl, const float* __restrict__ bias,
    float* __restrict__ out)
{
  __shared__ float slab[NS * E_EXP * TOKP];   // 69632 B
  __shared__ unsigned hist[E_EXP];

  const int tid  = threadIdx.x;
  const int wave = tid >> 6;
  const int lane = tid & 63;
  const int l15  = lane & 15;
  const int quad = lane >> 4;
  const int wg   = wave & 3;          // token group
  const int wsl  = wave >> 2;         // K slice
  const int k0   = wsl * (D_DIM / NS);
  const int tokw = blockIdx.x * TT + wg * 16;

  // A source: this lane's token row, this quad's 32-byte k-segment
  const float* xg = &x[(size_t)(tokw + l15) * D_DIM + k0 + quad * 8];

  // B source: frag-packed bf16 hi/lo (identical math to previous kernel)
  const unsigned short* bh_p = &ph[(((size_t)(k0 >> 5) * 4 + quad) * 64 + l15) * 8];
  const unsigned short* bl_p = &pl[(((size_t)(k0 >> 5) * 4 + quad) * 64 + l15) * 8];

  f32x4 acc[4];
  #pragma unroll
  for (int et = 0; et < 4; ++et) acc[et] = (f32x4){0.f, 0.f, 0.f, 0.f};

  // ---- prologue: load chunk 0's A ----
  float4 p0 = *(const float4*)xg;
  float4 p1 = *(const float4*)(xg + 4);

  #pragma unroll 1
  for (int c = 0; c < NCH; ++c) {
    // ---- all 8 B-frags for this chunk (L2-hot, 256 B segments) ----
    const unsigned short* ch = bh_p + (size_t)c * 2048;
    const unsigned short* cl = bl_p + (size_t)c * 2048;
    bf16x8 bh[4], bl[4];
    #pragma unroll
    for (int et = 0; et < 4; ++et) {
      bh[et] = *(const bf16x8*)&ch[et * 128];
      bl[et] = *(const bf16x8*)&cl[et * 128];
    }

    // ---- prefetch next chunk's A (in flight during convert + MFMA) ----
    float4 n0 = {0.f, 0.f, 0.f, 0.f}, n1 = {0.f, 0.f, 0.f, 0.f};
    if (c + 1 < NCH) {
      n0 = *(const float4*)(xg + (c + 1) * KC);
      n1 = *(const float4*)(xg + (c + 1) * KC + 4);
    }

    // ---- split current A chunk to hi/lo bf16 (register-only) ----
    const float xs[8] = {p0.x, p0.y, p0.z, p0.w, p1.x, p1.y, p1.z, p1.w};
    bf16x8 ah, al;
    #pragma unroll
    for (int j = 0; j < 8; ++j) {
      unsigned short h = bf16rne(xs[j]);
      ah[j] = (short)h;
      al[j] = (short)bf16rne(xs[j] - bf16f(h));
    }

    // ---- 12 MFMAs ----
    #pragma unroll
    for (int et = 0; et < 4; ++et) {
      acc[et] = __builtin_amdgcn_mfma_f32_16x16x32_bf16(ah, bh[et], acc[et], 0, 0, 0);
      acc[et] = __builtin_amdgcn_mfma_f32_16x16x32_bf16(al, bh[et], acc[et], 0, 0, 0);
      acc[et] = __builtin_amdgcn_mfma_f32_16x16x32_bf16(ah, bl[et], acc[et], 0, 0, 0);
    }

    p0 = n0; p1 = n1;   // dead on last iteration
  }

  // ---- acc -> LDS, expert-major: slab[wsl][e = et*16+l15][tok = wg*16+quad*4+r]
  // D frag: row(m)=quad*4+r (token), col(n)=l15 (expert) — acc[et][0..3] are 4
  // consecutive tokens at one expert column -> one b128 store each.
  #pragma unroll
  for (int et = 0; et < 4; ++et) {
    *(f32x4*)&slab[((size_t)(wsl * E_EXP + et * 16 + l15)) * TOKP + wg * 16 + quad * 4] = acc[et];
  }
  if (tid < E_EXP) hist[tid] = 0;
  __syncthreads();

  // ---- reduce 4 slices + bias into slice 0 (in place; each cell owned by one
  // thread). Summation order identical to old topk kernel: bias, +s0..+s3.
  {
    const int e  = tid >> 4;          // 0..63
    const int t4 = (tid & 15) * 4;    // 0..60
    f32x4 s0 = *(const f32x4*)&slab[(size_t)(0 * E_EXP + e) * TOKP + t4];
    f32x4 s1 = *(const f32x4*)&slab[(size_t)(1 * E_EXP + e) * TOKP + t4];
    f32x4 s2 = *(const f32x4*)&slab[(size_t)(2 * E_EXP + e) * TOKP + t4];
    f32x4 s3 = *(const f32x4*)&slab[(size_t)(3 * E_EXP + e) * TOKP + t4];
    const float b = bias[e];
    f32x4 v;
    #pragma unroll
    for (int j = 0; j < 4; ++j) v[j] = (((b + s0[j]) + s1[j]) + s2[j]) + s3[j];
    *(f32x4*)&slab[(size_t)(0 * E_EXP + e) * TOKP + t4] = v;
  }
  __syncthreads();

  if (tid >= TT) return;   // waves 1..15 done; wave 0 handles the 64 tokens

  const int t = tid;
  float l[E_EXP];
  #pragma unroll
  for (int j = 0; j < E_EXP; ++j) l[j] = slab[(size_t)j * TOKP + t];

  float tv[TOPK]; int tix[TOPK];
  unsigned long long used = 0ull;
  #pragma unroll
  for (int k = 0; k < TOPK; ++k) {
    float best = -INFINITY; int bi = 0;
    #pragma unroll
    for (int j = 0; j < E_EXP; ++j) {
      bool ok = (((used >> j) & 1ull) == 0ull) && (l[j] > best);  // strict >: lowest index wins ties
      best = ok ? l[j] : best;
      bi   = ok ? j : bi;
    }
    tv[k] = best; tix[k] = bi;
    used |= (1ull << bi);
  }

  float m = tv[0], s = 0.0f, w[TOPK];
  #pragma unroll
  for (int k = 0; k < TOPK; ++k) { w[k] = expf(tv[k] - m); s += w[k]; }
  float inv = 1.0f / s;

  const size_t gt = (size_t)blockIdx.x * TT + t;
  #pragma unroll
  for (int k = 0; k < TOPK; ++k) {
    out[gt * TOPK + k] = (float)tix[k];                                // indices as fp32
    out[(size_t)T_TOKENS * TOPK + gt * TOPK + k] = w[k] * inv;         // weights
  }

  #pragma unroll
  for (int k = 0; k < TOPK; ++k) atomicAdd(&hist[tix[k]], 1u);
  __threadfence_block();   // order wave-0's LDS atomics before its reads
  atomicAdd(&out[2 * (size_t)T_TOKENS * TOPK + t], (float)hist[t]);
}

extern "C" void kernel_launch(void* const* d_in, const int* in_sizes, int n_in,
                              void* d_out, int out_size, void* d_ws, size_t ws_size,
                              hipStream_t stream) {
  const float* x    = (const float*)d_in[0];
  const float* gw   = (const float*)d_in[1];
  const float* bias = (const float*)d_in[2];
  float* out  = (float*)d_out;

  // ws layout: ph (256 KB) | pl (256 KB)   (part buffer eliminated)
  unsigned short* ph = (unsigned short*)d_ws;
  unsigned short* pl = ph + (size_t)E_EXP * D_DIM;

  convert_g_kernel<<<dim3(E_EXP * D_DIM / 8 / 256), dim3(256), 0, stream>>>(
      gw, ph, pl, out + 2 * (size_t)T_TOKENS * TOPK);
  moe_fused_kernel<<<dim3(T_TOKENS / TT), dim3(1024), 0, stream>>>(
      x, ph, pl, bias, out);
}